// Round 4
// baseline (319.145 us; speedup 1.0000x reference)
//
#include <hip/hip_runtime.h>

// DigitConvolutionalModel R10 — persistent streaming GEMM with global_load_lds.
// conv+fc1 compose into W1eff (bias as k=784 row): out = relu(x@W1eff^T)@W2^T+b2.
//
// R6/R8/R9 post-mortem: three different overlap schedules all landed at
// ~105us for digit_gemm -> the invariant is the staging path itself
// (per-thread dwordx4 -> 100-VGPR array -> VALU cvt -> ds_write). R10
// replaces it with the DMA path the guide's A/B showed +67% on:
//   __builtin_amdgcn_global_load_lds(width=16): global -> LDS direct,
//   no VGPR round-trip, no staging VALU, loads survive barriers.
// Structure: 256 persistent blocks (1/CU), BM=16 images/tile, 16 tiles.
//   - xbuf[2][16][804] fp32 (stride 804: !=0 mod 32 -> sane b128 banks;
//     rows padded via EXEC-masked DMA lanes; pad dwords 784..799 hold the
//     static bias row {1.0,0,...} written once in the prologue)
//   - bf16 conversion happens in-register between ds_read and MFMA
//   - B fragments in registers (200 VGPR; 1 wave/SIMD -> budget 512)
//   - 2 barriers/iter: [vmcnt(0)+s_barrier] (DMAs landed, bufs swappable),
//     [lgkmcnt(0)+s_barrier] (hbuf visible for fc2)
// LDS: 2*16*804*4 + 16*132*4 + 4000 = 115,360 B -> 1 block/CU.

typedef short  s16x8 __attribute__((ext_vector_type(8)));   // 8 bf16
typedef float  f32x4 __attribute__((ext_vector_type(4)));   // 16x16 acc

#define BM    16    // images per tile
#define XP32  804   // xbuf row stride in floats (16B-aligned, !=0 mod 32)
#define HSTR  132   // hbuf row stride (floats)
#define NT    8     // prep emits 8 n-tiles (t=7 all zero)
#define KC    25    // k-chunks of 32: k<784 data, k==784 bias, k<800 zero
#define GRID  256   // persistent blocks, 1 per CU
#define SLOTS (BM * 201)          // 16B LDS slots per tile (201 = 804/4)
#define INSTS_PER_WAVE 13         // ceil(SLOTS/64/4) = 3216/256

__device__ __forceinline__ unsigned short f2bf_rtne(float f) {
    unsigned int u = __builtin_bit_cast(unsigned int, f);
    u = (u + 0x7fffu + ((u >> 16) & 1u)) >> 16;
    return (unsigned short)u;
}

// ---- prep: W1eff = conv (x) fc1 fold -> bf16 B-fragments + bias row --------
// bw[t][kc][lane][8]; lane(n=lane&15, q=lane>>4) holds
//   B[k = kc*32 + q*8 + j][n = t*16 + (lane&15)]
extern "C" __global__ void __launch_bounds__(256)
prep_w1eff(const float* __restrict__ W1, const float* __restrict__ cw9,
           const float* __restrict__ b1, unsigned short* __restrict__ bw)
{
    int id = blockIdx.x * 256 + threadIdx.x;
    if (id >= NT * KC * 64) return;
    int lane = id & 63;
    int kc   = (id >> 6) % KC;
    int t    = id / (KC * 64);
    int n    = t * 16 + (lane & 15);
    int k0   = kc * 32 + (lane >> 4) * 8;

    float cw[9];
#pragma unroll
    for (int i = 0; i < 9; ++i) cw[i] = cw9[i];

    unsigned short v[8];
#pragma unroll
    for (int j = 0; j < 8; ++j) {
        int k = k0 + j;
        float f = 0.f;
        if (n < 100) {
            if (k < 784) {
                int i = k / 28, jj = k % 28;
                for (int dr = 0; dr < 3; ++dr)
                    for (int dc = 0; dc < 3; ++dc) {
                        int a = i - dr, b = jj - dc;
                        if (a >= 0 && a < 26 && b >= 0 && b < 26)
                            f = fmaf(W1[(size_t)n * 676 + a * 26 + b],
                                     cw[dr * 3 + dc], f);
                    }
            } else if (k == 784) {
                f = b1[n];            // bias row; A supplies 1.0 at k=784
            }                         // 785..799: zero
        }
        v[j] = f2bf_rtne(f);
    }
    *(uint4*)(bw + (size_t)id * 8) = *(const uint4*)v;
}

#define MFMA(a, b, c) __builtin_amdgcn_mfma_f32_16x16x32_bf16(a, b, c, 0, 0, 0)

// 16B global->LDS DMA (per-lane global src, wave-uniform LDS base + lane*16)
__device__ __forceinline__ void gld_lds16(const float* gsrc, float* ldst) {
    __builtin_amdgcn_global_load_lds(
        (const __attribute__((address_space(1))) unsigned int*)gsrc,
        (__attribute__((address_space(3))) unsigned int*)ldst, 16, 0, 0);
}

// pack 8 fp32 -> 8 bf16 (round-half-up, numerics identical to R6-R9 staging)
__device__ __forceinline__ s16x8 cvt8(float4 a, float4 b) {
    unsigned int ax = __builtin_bit_cast(unsigned int, a.x) + 0x8000u;
    unsigned int ay = __builtin_bit_cast(unsigned int, a.y) + 0x8000u;
    unsigned int az = __builtin_bit_cast(unsigned int, a.z) + 0x8000u;
    unsigned int aw = __builtin_bit_cast(unsigned int, a.w) + 0x8000u;
    unsigned int bx = __builtin_bit_cast(unsigned int, b.x) + 0x8000u;
    unsigned int by = __builtin_bit_cast(unsigned int, b.y) + 0x8000u;
    unsigned int bz = __builtin_bit_cast(unsigned int, b.z) + 0x8000u;
    unsigned int bw_ = __builtin_bit_cast(unsigned int, b.w) + 0x8000u;
    uint4 u;
    u.x = (ax >> 16) | (ay & 0xffff0000u);
    u.y = (az >> 16) | (aw & 0xffff0000u);
    u.z = (bx >> 16) | (by & 0xffff0000u);
    u.w = (bz >> 16) | (bw_ & 0xffff0000u);
    return __builtin_bit_cast(s16x8, u);
}

// ---------------------------- main kernel ----------------------------------
extern "C" __global__ void __launch_bounds__(256, 1)
digit_gemm(const float* __restrict__ x,
           const unsigned short* __restrict__ bw,
           const float* __restrict__ W2,
           const float* __restrict__ b2,
           float* __restrict__ out,
           int ntiles)
{
    __shared__ __align__(16) float xbuf[2][BM * XP32];   // 102,912 B
    __shared__ __align__(16) float w2buf[10 * 100];      //   4,000 B
    __shared__ __align__(16) float hbuf[BM * HSTR];      //   8,448 B

    const int tid  = threadIdx.x;
    const int lane = tid & 63;
    const int wv   = tid >> 6;       // 0..3
    const int q    = lane >> 4;      // k-quarter
    const int mn   = lane & 15;      // m row / n col within tile
    const int tile0 = blockIdx.x * ntiles;

    // -------- prologue ------------------------------------------------------
    // B fragments -> registers (once; bw is L2-resident, shared by all blocks)
    const uint4* bwv = (const uint4*)bw;
    const int t0 = wv, t1 = wv + 4;            // t1==7 (wave 3) is zero tile
    uint4 br0[KC], br1[KC];
#pragma unroll
    for (int kc = 0; kc < KC; ++kc) {
        br0[kc] = bwv[(t0 * KC + kc) * 64 + lane];
        br1[kc] = bwv[(t1 * KC + kc) * 64 + lane];
    }

    // W2 -> LDS (once); b2 -> per-thread reg for the single fc2 slot
#pragma unroll
    for (int i = 0; i < 4; ++i) {
        int j = tid + 256 * i;
        if (j < 1000) w2buf[j] = W2[j];
    }
    const bool has0 = (tid < BM * 10);
    const int mi0 = tid / 10, o0 = tid - mi0 * 10;
    const float bb0 = has0 ? b2[o0] : 0.f;

    // static K-pad dwords [784,800) for BOTH buffers: 1.0 at 784, zeros after
    for (int s = tid; s < 2 * BM * 16; s += 256) {
        int b = s >> 8, r = (s >> 4) & (BM - 1), d = s & 15;
        xbuf[b][r * XP32 + 784 + d] = (d == 0) ? 1.0f : 0.f;
    }

    // DMA-issue helper inputs: wave handles slots [ (wv*13+i)*64 + lane ]
    // slot -> row m = slot/201, col c4 = slot%201; data iff c4 < 196.
    // first tile -> buf 0
    {
        const float* xg = x + (size_t)tile0 * BM * 784;
#pragma unroll
        for (int i = 0; i < INSTS_PER_WAVE; ++i) {
            int sb   = (wv * INSTS_PER_WAVE + i) * 64;
            int slot = sb + lane;
            int m    = slot / 201, c4 = slot - m * 201;
            if (slot < SLOTS && c4 < 196)
                gld_lds16(xg + (size_t)m * 784 + c4 * 4, &xbuf[0][sb * 4]);
        }
    }
    asm volatile("s_waitcnt vmcnt(0)" ::: "memory");
    __syncthreads();                       // pads + tile-0 DMA all visible

    // -------- persistent tile loop ------------------------------------------
    for (int t = 0; t < ntiles; ++t) {
        const int cur = t & 1;
        const int m0  = (tile0 + t) * BM;

        // issue next tile's DMA into the other buffer (safe: all waves have
        // passed the barrier ending iter t-1, so buf^1 reads are complete)
        if (t + 1 < ntiles) {
            const float* xg = x + (size_t)(tile0 + t + 1) * BM * 784;
#pragma unroll
            for (int i = 0; i < INSTS_PER_WAVE; ++i) {
                int sb   = (wv * INSTS_PER_WAVE + i) * 64;
                int slot = sb + lane;
                int m    = slot / 201, c4 = slot - m * 201;
                if (slot < SLOTS && c4 < 196)
                    gld_lds16(xg + (size_t)m * 784 + c4 * 4,
                              &xbuf[cur ^ 1][sb * 4]);
            }
        }

        // ---- MFMA from LDS (fp32 -> bf16 in-reg), B from registers --------
        f32x4 acc0, acc1;
#pragma unroll
        for (int i = 0; i < 4; ++i) { acc0[i] = 0.f; acc1[i] = 0.f; }
        const float* ar = &xbuf[cur][mn * XP32 + q * 8];
#pragma unroll
        for (int kc = 0; kc < KC; ++kc) {
            float4 f0 = *(const float4*)(ar + kc * 32);
            float4 f1 = *(const float4*)(ar + kc * 32 + 4);
            s16x8 av = cvt8(f0, f1);
            acc0 = MFMA(av, __builtin_bit_cast(s16x8, br0[kc]), acc0);
            if (wv < 3)
                acc1 = MFMA(av, __builtin_bit_cast(s16x8, br1[kc]), acc1);
        }

        // ---- ReLU -> hbuf; C/D row(image) = q*4 + r, col(neuron) = mn ------
#pragma unroll
        for (int r = 0; r < 4; ++r) {
            int row = q * 4 + r;
            float z;
            z = acc0[r]; z = z > 0.f ? z : 0.f; hbuf[row * HSTR + t0 * 16 + mn] = z;
            if (wv < 3) {
                z = acc1[r]; z = z > 0.f ? z : 0.f; hbuf[row * HSTR + t1 * 16 + mn] = z;
            }
        }
        asm volatile("s_waitcnt lgkmcnt(0)" ::: "memory");
        __builtin_amdgcn_s_barrier();           // hbuf visible

        // ---- fc2 (fp32 VALU, W2 from LDS) + store --------------------------
        if (has0) {
            const float4* hv = (const float4*)(hbuf + mi0 * HSTR);
            const float4* w2 = (const float4*)(w2buf + o0 * 100);
            float s = bb0;
#pragma unroll
            for (int g = 0; g < 25; ++g) {
                float4 h4 = hv[g], w4 = w2[g];
                s += h4.x * w4.x + h4.y * w4.y + h4.z * w4.z + h4.w * w4.w;
            }
            out[(size_t)(m0 + mi0) * 10 + o0] = s;
        }

        // ---- end of iter: own DMAs landed, then block-wide rendezvous ------
        asm volatile("s_waitcnt vmcnt(0)" ::: "memory");
        __builtin_amdgcn_s_barrier();           // next tile ready, bufs swap
    }
}

extern "C" void kernel_launch(void* const* d_in, const int* in_sizes, int n_in,
                              void* d_out, int out_size, void* d_ws, size_t ws_size,
                              hipStream_t stream) {
    const float* x  = (const float*)d_in[0];
    const float* cw = (const float*)d_in[1];
    const float* W1 = (const float*)d_in[2];
    const float* b1 = (const float*)d_in[3];
    const float* W2 = (const float*)d_in[4];
    const float* b2 = (const float*)d_in[5];
    float* out = (float*)d_out;
    unsigned short* bw = (unsigned short*)d_ws;    // NT*KC*64*8*2 = 204,800 B

    const int B = in_sizes[0] / 784;               // 65536
    const int ntiles = (B / BM) / GRID;            // 4096 tiles / 256 = 16

    hipLaunchKernelGGL(prep_w1eff, dim3((NT * KC * 64 + 255) / 256), dim3(256),
                       0, stream, W1, cw, b1, bw);
    hipLaunchKernelGGL(digit_gemm, dim3(GRID), dim3(256), 0, stream,
                       x, bw, W2, b2, out, ntiles);
}